// Round 1
// 215.400 us; speedup vs baseline: 1.1072x; 1.1072x over previous
//
#include <hip/hip_runtime.h>

#define N_NODES 100000
#define N_EDGES 1600000
#define D 128
#define RPB 64                        // node rows per bucket
#define NBUCKET 1563                  // ceil(N_NODES / RPB)
#define NBLK 196                      // edge chunks
#define EPB 8192                      // edges per chunk
#define AGG_CAP 2048                  // max edges per bucket (mean 1024, +32 sigma)
#define XCB 3125                      // xconv blocks (3.2M float4 / 1024)
#define SCAN_PAD 1792                 // 256*7 >= NBUCKET

constexpr float LN_EPS   = 1e-5f;
constexpr float MEAN_EPS = 1e-8f;

typedef __attribute__((ext_vector_type(8))) short bf16x8;
typedef __attribute__((ext_vector_type(4))) float f32x4;

__device__ inline float bf2f(unsigned short h) {
  union { unsigned u; float f; } v; v.u = (unsigned)h << 16; return v.f;
}
__device__ inline float bflo(unsigned p) {
  union { unsigned u; float f; } v; v.u = p << 16; return v.f;
}
__device__ inline float bfhi(unsigned p) {
  union { unsigned u; float f; } v; v.u = p & 0xFFFF0000u; return v.f;
}
__device__ inline unsigned short f2bf(float f) {
  union { float f; unsigned u; } v; v.f = f;
  return (unsigned short)((v.u + 0x7FFFu + ((v.u >> 16) & 1u)) >> 16);
}

// ---------------------------------------------------------------------------
// Fused prep: blocks [0,NBLK) = per-chunk bucket sort (hist -> local scan ->
// LDS scatter -> dense coalesced write + packed/transposed chunkoff).
// [NBLK,NBLK+XCB) = x->bf16. Last 16 = W concat + bias.
// ---------------------------------------------------------------------------
__global__ __launch_bounds__(256) void prep_sort(
    const float* __restrict__ x, const int* __restrict__ ei,
    const float* __restrict__ Wself, const float* __restrict__ Wagg,
    const float* __restrict__ bself, const float* __restrict__ bagg,
    unsigned short* __restrict__ xb, unsigned short* __restrict__ wcat,
    float* __restrict__ bsum, unsigned* __restrict__ ent_sorted,
    int* __restrict__ chunkoff) {
  __shared__ int ent_s[EPB];        // 32 KB
  __shared__ int cnt_s[SCAN_PAD];   // 7 KB
  __shared__ int off_s[SCAN_PAD];   // 7 KB (becomes cursors after chunkoff write)
  __shared__ int sb[256];
  const int bid = blockIdx.x;
  const int t = threadIdx.x;

  if (bid < NBLK) {
    const int ebase = bid * EPB;
    const int nch = min(EPB, N_EDGES - ebase);       // last chunk: 2560
    const int base4 = bid * (EPB / 4);
    const int end4 = base4 + (nch >> 2);             // nch divisible by 4

    for (int i = t; i < SCAN_PAD; i += 256) cnt_s[i] = 0;
    __syncthreads();

    // pass 1: histogram
#pragma unroll
    for (int k = 0; k < EPB / 1024; ++k) {
      int i4 = base4 + k * 256 + t;
      if (i4 < end4) {
        int4 r = ((const int4*)ei)[i4];
        atomicAdd(&cnt_s[r.x >> 6], 1);
        atomicAdd(&cnt_s[r.y >> 6], 1);
        atomicAdd(&cnt_s[r.z >> 6], 1);
        atomicAdd(&cnt_s[r.w >> 6], 1);
      }
    }
    __syncthreads();

    // blocked exclusive scan over SCAN_PAD (=256*7) entries
    int psum = 0;
#pragma unroll
    for (int i = 0; i < 7; ++i) psum += cnt_s[t * 7 + i];
    sb[t] = psum;
    __syncthreads();
    for (int off = 1; off < 256; off <<= 1) {
      int u = (t >= off) ? sb[t - off] : 0;
      __syncthreads();
      sb[t] += u;
      __syncthreads();
    }
    int run = sb[t] - psum;
#pragma unroll
    for (int i = 0; i < 7; ++i) {
      off_s[t * 7 + i] = run;
      run += cnt_s[t * 7 + i];
    }
    __syncthreads();

    // packed transposed chunkoff: chunkoff[b*NBLK + chunk] = beg | (len<<14)
    // (written BEFORE scatter destroys off_s; buffer is 1.2 MB -> L2-resident)
    for (int b = t; b < NBUCKET; b += 256)
      chunkoff[b * NBLK + bid] = off_s[b] | (cnt_s[b] << 14);
    __syncthreads();

    // pass 2: LDS scatter into bucket-sorted order (off_s as cursors)
#pragma unroll
    for (int k = 0; k < EPB / 1024; ++k) {
      int i4 = base4 + k * 256 + t;
      if (i4 < end4) {
        int4 r = ((const int4*)ei)[i4];
        int4 c = ((const int4*)(ei + N_EDGES))[i4];
        int p0 = atomicAdd(&off_s[r.x >> 6], 1);
        ent_s[p0] = ((r.x & 63) << 17) | c.x;
        int p1 = atomicAdd(&off_s[r.y >> 6], 1);
        ent_s[p1] = ((r.y & 63) << 17) | c.y;
        int p2 = atomicAdd(&off_s[r.z >> 6], 1);
        ent_s[p2] = ((r.z & 63) << 17) | c.z;
        int p3 = atomicAdd(&off_s[r.w >> 6], 1);
        ent_s[p3] = ((r.w & 63) << 17) | c.w;
      }
    }
    __syncthreads();

    // dense coalesced write-out
    for (int i = t; i < nch; i += 256)
      ent_sorted[ebase + i] = (unsigned)ent_s[i];
  } else if (bid < NBLK + XCB) {
    // ---- xconv: 4 float4 per thread -> bf16x4
    const int base = (bid - NBLK) * 1024;
#pragma unroll
    for (int k = 0; k < 4; ++k) {
      int i4 = base + k * 256 + t;   // XCB*1024 == 3.2M exact
      float4 v = ((const float4*)x)[i4];
      ushort4 o;
      o.x = f2bf(v.x); o.y = f2bf(v.y); o.z = f2bf(v.z); o.w = f2bf(v.w);
      ((ushort4*)xb)[i4] = o;
    }
  } else {
    // ---- wconv: 16 blocks cover 128x256 weights
    const int blk = bid - NBLK - XCB;
#pragma unroll
    for (int k = 0; k < 8; ++k) {
      int idx = blk * 2048 + k * 256 + t;
      int o = idx >> 8, kc = idx & 255;
      float v = (kc < 128) ? Wself[o * 128 + kc] : Wagg[o * 128 + (kc - 128)];
      wcat[o * 256 + kc] = f2bf(v);
    }
    if (blk == 0 && t < 128) bsum[t] = bself[t] + bagg[t];
  }
}

// ---------------------------------------------------------------------------
// Aggregate: block b reads its bucket's packed (beg,len) row (coalesced),
// scans, copies slices into LDS, row counting sort, then wave-per-edge
// gather: lane l owns cols 2l..2l+1, 8 loads in flight, no cross-lane
// reduction. Mean written bf16 into first 256B of node's out row.
// ---------------------------------------------------------------------------
__global__ __launch_bounds__(256) void aggregate(
    const unsigned short* __restrict__ xb, const unsigned* __restrict__ ent_sorted,
    const int* __restrict__ chunkoff, float* out) {
  __shared__ int ent_s[AGG_CAP];   // 8 KB
  __shared__ int col_s[AGG_CAP];   // 8 KB
  __shared__ int sb[256];
  __shared__ int cnt_s[RPB];
  __shared__ int off_s[RPB];
  __shared__ int cur_s[RPB];

  const int b = blockIdx.x;
  const int t = threadIdx.x;

  // packed slice info (one coalesced int per chunk) + scan of lengths
  int beg = 0, len = 0;
  if (t < NBLK) {
    int pk = chunkoff[b * NBLK + t];
    beg = pk & 16383;
    len = pk >> 14;
  }
  sb[t] = len;
  __syncthreads();
  for (int off = 1; off < 256; off <<= 1) {
    int u = (t >= off) ? sb[t - off] : 0;
    __syncthreads();
    sb[t] += u;
    __syncthreads();
  }
  int n = sb[255]; if (n > AGG_CAP) n = AGG_CAP;
  int dst = sb[t] - len;
  // parallel slice copy (196 threads, ~5 entries each, contiguous reads)
  if (t < NBLK) {
    const unsigned* src = ent_sorted + t * EPB + beg;
    for (int i = 0; i < len; ++i)
      if (dst + i < AGG_CAP) ent_s[dst + i] = (int)src[i];
  }
  __syncthreads();

  // row counting sort
  if (t < RPB) cnt_s[t] = 0;
  __syncthreads();
  for (int i = t; i < n; i += 256) atomicAdd(&cnt_s[ent_s[i] >> 17], 1);
  __syncthreads();
  if (t < RPB) off_s[t] = cnt_s[t];
  __syncthreads();
  for (int off = 1; off < RPB; off <<= 1) {
    int u = 0;
    if (t < RPB && t >= off) u = off_s[t - off];
    __syncthreads();
    if (t < RPB) off_s[t] += u;
    __syncthreads();
  }
  int excl = 0;
  if (t < RPB) excl = off_s[t] - cnt_s[t];
  __syncthreads();
  if (t < RPB) { off_s[t] = excl; cur_s[t] = excl; }
  __syncthreads();
  for (int i = t; i < n; i += 256) {
    int e = ent_s[i];
    int pos = atomicAdd(&cur_s[e >> 17], 1);
    col_s[pos] = e & 0x1FFFF;
  }
  __syncthreads();

  // gather: one wave per row iteration; lane l owns columns 2l, 2l+1.
  // Whole wave works one edge -> uniform control flow, coalesced 256B reads,
  // 8 loads in flight, zero cross-lane reduction.
  const int w = t >> 6, lane = t & 63;
  const int nodebase = b << 6;
  for (int lrow = w; lrow < RPB; lrow += 4) {
    int node = nodebase + lrow;
    if (node >= N_NODES) break;
    int rbeg = off_s[lrow];
    int deg = cnt_s[lrow];
    float a0 = 0.f, a1 = 0.f;
    int j = 0;
    for (; j + 8 <= deg; j += 8) {
      unsigned p[8];
#pragma unroll
      for (int u = 0; u < 8; ++u) {
        int col = col_s[rbeg + j + u];                       // uniform -> broadcast
        p[u] = *(const unsigned*)(xb + (size_t)col * D + lane * 2);
      }
#pragma unroll
      for (int u = 0; u < 8; ++u) { a0 += bflo(p[u]); a1 += bfhi(p[u]); }
    }
    if (j + 4 <= deg) {
      unsigned p[4];
#pragma unroll
      for (int u = 0; u < 4; ++u) {
        int col = col_s[rbeg + j + u];
        p[u] = *(const unsigned*)(xb + (size_t)col * D + lane * 2);
      }
#pragma unroll
      for (int u = 0; u < 4; ++u) { a0 += bflo(p[u]); a1 += bfhi(p[u]); }
      j += 4;
    }
    for (; j < deg; ++j) {
      int col = col_s[rbeg + j];
      unsigned p = *(const unsigned*)(xb + (size_t)col * D + lane * 2);
      a0 += bflo(p); a1 += bfhi(p);
    }
    float inv = 1.0f / ((float)deg + MEAN_EPS);
    unsigned o = (unsigned)f2bf(a0 * inv) | ((unsigned)f2bf(a1 * inv) << 16);
    ((unsigned*)(out + (size_t)node * D))[lane] = o;
  }
}

// ---------------------------------------------------------------------------
// MFMA GEMM: C[100000x128] = [x_bf16 | mean_bf16] (K=256) @ Wcat^T + ReLU + LN
// v2: B-only LDS (67.6 KB -> 2 blocks/CU), A streamed global->frags (each row
// read once), each wave owns 16 full rows -> in-register LN, no hS, no
// epilogue barriers.
// ---------------------------------------------------------------------------
__global__ __launch_bounds__(512, 4) void gemm_mfma_ln(
    const unsigned short* __restrict__ xb, const float* out_mean,
    const unsigned short* __restrict__ wcat, const float* __restrict__ bsum,
    const float* __restrict__ gamma, const float* __restrict__ beta,
    float* out) {
  __shared__ unsigned short Bs[128 * 264];   // 67.6 KB
  __shared__ float bias_s[128];

  const int t = threadIdx.x;
  const int w = t >> 6, lane = t & 63;
  const int q = lane >> 4, s = lane & 15;
  const int base = blockIdx.x * 128;

  if (t < 128) bias_s[t] = bsum[t];

  // stage B (all 128x256 of wcat), +8 ushort row pad
#pragma unroll
  for (int r = 0; r < 8; ++r) {
    int f = r * 512 + t;
    int row = f >> 5, c = f & 31;
    uint4 v = *(const uint4*)(wcat + row * 256 + c * 8);
    *(uint4*)(Bs + row * 264 + c * 8) = v;
  }

  // A fragments direct from global: lane's A-row = base + w*16 + s
  const int arow = base + w * 16 + s;
  const int asafe = (arow < N_NODES) ? arow : 0;
  const unsigned short* xrow = xb + (size_t)asafe * 128;
  const unsigned short* mrow = (const unsigned short*)(out_mean + (size_t)asafe * 128);
  bf16x8 a[8];
#pragma unroll
  for (int kk = 0; kk < 4; ++kk)
    a[kk] = *(const bf16x8*)(xrow + kk * 32 + q * 8);
#pragma unroll
  for (int kk = 0; kk < 4; ++kk)
    a[4 + kk] = *(const bf16x8*)(mrow + kk * 32 + q * 8);

  __syncthreads();

  f32x4 acc[8];
#pragma unroll
  for (int j = 0; j < 8; ++j) acc[j] = (f32x4)(0.0f);

#pragma unroll
  for (int kk = 0; kk < 8; ++kk) {
    const int ko = kk * 32 + q * 8;
#pragma unroll
    for (int j = 0; j < 8; ++j) {
      bf16x8 bv = *(const bf16x8*)(Bs + (j * 16 + s) * 264 + ko);
      acc[j] = __builtin_amdgcn_mfma_f32_16x16x32_bf16(a[kk], bv, acc[j], 0, 0, 0);
    }
  }

  // epilogue fully in registers: bias + relu, then LN per row.
  // C layout: value (row = q*4 + r, col = j*16 + s) in acc[j][r].
#pragma unroll
  for (int j = 0; j < 8; ++j) {
    float bb = bias_s[j * 16 + s];
#pragma unroll
    for (int r = 0; r < 4; ++r)
      acc[j][r] = fmaxf(acc[j][r] + bb, 0.0f);
  }

  float g[8], be[8];
#pragma unroll
  for (int j = 0; j < 8; ++j) {
    g[j]  = gamma[j * 16 + s];
    be[j] = beta[j * 16 + s];
  }

#pragma unroll
  for (int r = 0; r < 4; ++r) {
    float s1 = 0.f, s2 = 0.f;
#pragma unroll
    for (int j = 0; j < 8; ++j) {
      float h = acc[j][r];
      s1 += h; s2 += h * h;
    }
#pragma unroll
    for (int m = 1; m < 16; m <<= 1) {
      s1 += __shfl_xor(s1, m, 64);
      s2 += __shfl_xor(s2, m, 64);
    }
    int node = base + w * 16 + q * 4 + r;
    if (node < N_NODES) {
      float mu = s1 * (1.0f / 128.0f);
      float var = s2 * (1.0f / 128.0f) - mu * mu;
      float rstd = rsqrtf(var + LN_EPS);
      float* orow = out + (size_t)node * 128;
#pragma unroll
      for (int j = 0; j < 8; ++j)
        orow[j * 16 + s] = (acc[j][r] - mu) * rstd * g[j] + be[j];
    }
  }
}

extern "C" void kernel_launch(void* const* d_in, const int* in_sizes, int n_in,
                              void* d_out, int out_size, void* d_ws, size_t ws_size,
                              hipStream_t stream) {
  const float* x     = (const float*)d_in[0];
  const int*   ei    = (const int*)d_in[1];
  const float* Wagg  = (const float*)d_in[2];
  const float* bagg  = (const float*)d_in[3];
  const float* Wself = (const float*)d_in[4];
  const float* bself = (const float*)d_in[5];
  const float* gamma = (const float*)d_in[6];
  const float* beta  = (const float*)d_in[7];
  float* out = (float*)d_out;

  // ws: xb | wcat | bsum | ent_sorted | chunkoff   (~33.3 MB)
  unsigned short* xb   = (unsigned short*)d_ws;                 // 25.6 MB
  unsigned short* wcat = xb + (size_t)N_NODES * D;              // 64 KB
  float* bsum      = (float*)(wcat + 128 * 256);                // 512 B
  unsigned* ent_sorted = (unsigned*)(bsum + 128);               // NBLK*EPB u32 (6.4 MB)
  int* chunkoff    = (int*)(ent_sorted + (size_t)NBLK * EPB);   // NBUCKET*NBLK (1.2 MB)

  prep_sort<<<NBLK + XCB + 16, 256, 0, stream>>>(
      x, ei, Wself, Wagg, bself, bagg, xb, wcat, bsum, ent_sorted, chunkoff);

  aggregate<<<NBUCKET, 256, 0, stream>>>(xb, ent_sorted, chunkoff, out);

  gemm_mfma_ln<<<(N_NODES + 127) / 128, 512, 0, stream>>>(
      xb, out, wcat, bsum, gamma, beta, out);
}